// Round 2
// baseline (499.676 us; speedup 1.0000x reference)
//
#include <hip/hip_runtime.h>
#include <math.h>

#define L2C   65536
#define NC    (2 * L2C)
#define FINC  8
#define FOUTC 8
#define KC    13
#define BLOCK 256         // 4 waves = 4 edges per block (1 edge per wave)
#define EPB   4

constexpr double E_D = 2.71828182845904523536;
constexpr float SCALE_F = (float)((2.0 + 2.0 * E_D) / (E_D - 1.0));

// Sizes for the bitmap path (R9).
#define WORDS_PER_BRANCH        ((size_t)L2C * FOUTC * FINC * KC)      // 54,525,952 mask elements
#define PACK_THREADS_PER_BRANCH (WORDS_PER_BRANCH / 4)                 // 13,631,488 (4 flags/thread)
#define BITMAP_BYTES_PER_BRANCH (WORDS_PER_BRANCH / 8)                 // 6,815,744
#define XT_BYTES                ((size_t)NC * FINC * 4)                // 4 MiB

// d_ws layout: [0, 4MiB) xt (N, FIN); [4MiB, +13.6MB) mask bitmap (hor then vert).

// x (FIN, N) -> xt (N, FIN): a gathered column becomes one 32 B segment.
__global__ __launch_bounds__(256)
void transpose_x_kernel(const float* __restrict__ x, float* __restrict__ xt) {
    int n = blockIdx.x * 256 + threadIdx.x;
    float v[FINC];
#pragma unroll
    for (int i = 0; i < FINC; ++i) v[i] = x[(size_t)i * NC + n];
    float4* dst = reinterpret_cast<float4*>(xt + ((size_t)n << 3));
    dst[0] = make_float4(v[0], v[1], v[2], v[3]);
    dst[1] = make_float4(v[4], v[5], v[6], v[7]);
}

// R9: R1 counters showed edge_conv latency-bound (HBM 27%, VALU 51%, occ 84%,
// nothing saturated) — the serial 12-step shfl+ballot mask-redistribution
// chain (forced by the 13-bits-per-lane vs 16-bytes-per-lane mismatch) was
// the critical path, not load width. Fix: pack masks to 1 bit/flag in a
// separate PURE-STREAM kernel (unit-stride uint4 loads, one shfl_down, byte
// store — trivially BW-bound), then the conv kernel reads each lane's 13
// bits directly (2 dword loads from the 13.6 MB L2-warm bitmap): zero
// cross-lane ops in the mask path.
//
// Bit order: flat. bit g of branch bitmap = (mask element g != 0), where
// g = be*832 + (o*8+i)*13 + k. Pack thread t produces flags 4t..4t+3 as a
// nibble; one __shfl_down pairs nibbles; even threads store byte t/2.
__global__ __launch_bounds__(256)
void pack_mask_kernel(const unsigned char* __restrict__ mh,
                      const unsigned char* __restrict__ mv,
                      unsigned char* __restrict__ bm)
{
    // Mask-encoding probe (same logic as the proven R3/R8 conv probe): for
    // int32/float32 0/1 masks every byte at offset%4==1 is zero; for 1-byte
    // bools they're random 0/1. Grid-uniform (all waves read same window).
    const int lane = threadIdx.x & 63;
    const unsigned char probe = mh[(size_t)(lane * 4 + 1)];
    const bool words = (__ballot(probe != 0) == 0ull);

    const size_t t   = (size_t)blockIdx.x * 256 + threadIdx.x;
    const bool   hor = t < PACK_THREADS_PER_BRANCH;
    const unsigned char* src = hor ? mh : mv;
    const size_t u   = hor ? t : t - PACK_THREADS_PER_BRANCH;
    unsigned char* dst = bm + (hor ? 0 : BITMAP_BYTES_PER_BRANCH);

    unsigned int nib;
    if (words) {
        // 4 int32 flags, 16 B/lane unit-stride (peak-BW pattern).
        const uint4 v = reinterpret_cast<const uint4*>(src)[u];
        nib =  (unsigned int)(v.x != 0u)
            | ((unsigned int)(v.y != 0u) << 1)
            | ((unsigned int)(v.z != 0u) << 2)
            | ((unsigned int)(v.w != 0u) << 3);
    } else {
        // 4 bool bytes, 4 B/lane unit-stride (cold path).
        const unsigned int v = reinterpret_cast<const unsigned int*>(src)[u];
        nib =  (unsigned int)((v & 0x000000FFu) != 0u)
            | ((unsigned int)((v & 0x0000FF00u) != 0u) << 1)
            | ((unsigned int)((v & 0x00FF0000u) != 0u) << 2)
            | ((unsigned int)((v & 0xFF000000u) != 0u) << 3);
    }
    // Pair nibbles: byte b = flags 8b..8b+7 (flat little-endian order).
    nib |= ((unsigned int)__shfl_down((int)nib, 1)) << 4;
    if ((u & 1) == 0) dst[u >> 1] = (unsigned char)nib;
}

// One wave per edge. lane = o*8 + i. Mask bits come from the packed bitmap:
// lane's 13 bits start at flat bit g = be*832 + lane*13 -> 2 dword loads.
__global__ __launch_bounds__(BLOCK)
void edge_conv_bitmap_kernel(const float* __restrict__ xt,
                             const float* __restrict__ Wh, const float* __restrict__ Wv,
                             const float* __restrict__ bh, const float* __restrict__ bv,
                             const unsigned char* __restrict__ bm,
                             const int* __restrict__ kh, const int* __restrict__ kv,
                             float* __restrict__ out)
{
    __shared__ float Wsh[FOUTC * FINC * KC];   // flat [o][i][k], same as input

    const int tid  = threadIdx.x;
    const int lane = tid & 63;
    const int o    = lane >> 3;
    const int i    = lane & 7;

    const int blk = blockIdx.x;
    const int blocks_per_branch = L2C / EPB;   // 16384
    const bool hor = (blk < blocks_per_branch);

    const float* W    = hor ? Wh : Wv;
    const float* bias = hor ? bh : bv;
    const int*   ker  = hor ? kh : kv;
    const int bblk = hor ? blk : blk - blocks_per_branch;
    const int be   = bblk * EPB + (tid >> 6);  // edge index within branch
    const int col  = hor ? be : (be + L2C);    // edge lists are arange / arange+L2

    // Stage W into LDS (identical flat layout).
    for (int j = tid; j < FOUTC * FINC * KC; j += BLOCK) Wsh[j] = W[j];

    // Mask bits: flat bit index g = be*832 + lane*13. (g&31)+12 <= 43 so the
    // bits span at most 2 dwords. The +1 dword read can touch 4 B past the
    // vert bitmap for the last edge — covered by ws padding.
    const unsigned int* bmw = reinterpret_cast<const unsigned int*>(bm)
                              + (hor ? 0 : (BITMAP_BYTES_PER_BRANCH / 4));
    const int g = be * (FOUTC * FINC * KC) + lane * KC;
    const unsigned int blo = bmw[g >> 5];
    const unsigned int bhi = bmw[(g >> 5) + 1];
    const unsigned int mbits =
        (unsigned int)((((unsigned long long)bhi << 32) | blo) >> (g & 31)) & 0x1FFFu;

    // Kernel column indices (wave-uniform address).
    int cols[KC];
#pragma unroll
    for (int k = 0; k < KC; ++k) cols[k] = ker[(size_t)be * KC + k];

    __syncthreads();

    float acc = 0.0f;
#pragma unroll
    for (int k = 0; k < KC; ++k) {
        const float xv = xt[((size_t)cols[k] << 3) + i];   // one 32 B seg / wave / k
        const float wk = Wsh[lane * KC + k];               // 2-way LDS alias: free
        const float wm = ((mbits >> k) & 1u) ? wk : 0.0f;
        acc = fmaf(wm, xv, acc);
    }

    // Reduce over i (lanes o*8 .. o*8+7).
    acc += __shfl_xor(acc, 1);
    acc += __shfl_xor(acc, 2);
    acc += __shfl_xor(acc, 4);

    if (i == 0) {
        const float z   = acc + bias[o];
        const float sig = 1.0f / (1.0f + __expf(-z));
        out[(size_t)o * NC + col] = (sig - 0.5f) * SCALE_F;
    }
}

// ---- Fallback (proven R8 structure, 451 µs total) — used only if d_ws is
// too small for the bitmap. Unchanged.
__global__ __launch_bounds__(BLOCK)
void edge_conv_kernel(const float* __restrict__ xt,
                      const float* __restrict__ Wh, const float* __restrict__ Wv,
                      const float* __restrict__ bh, const float* __restrict__ bv,
                      const unsigned char* __restrict__ mh,
                      const unsigned char* __restrict__ mv,
                      const int* __restrict__ kh, const int* __restrict__ kv,
                      float* __restrict__ out)
{
    __shared__ float Wsh[FOUTC * FINC * KC];

    const int tid  = threadIdx.x;
    const int lane = tid & 63;
    const int o    = lane >> 3;
    const int i    = lane & 7;

    const int blk = blockIdx.x;
    const int blocks_per_branch = L2C / EPB;
    const bool hor = (blk < blocks_per_branch);

    const float*         W    = hor ? Wh  : Wv;
    const float*         bias = hor ? bh  : bv;
    const unsigned char* mask = hor ? mh  : mv;
    const int*           ker  = hor ? kh  : kv;
    const int bblk = hor ? blk : blk - blocks_per_branch;
    const int be   = bblk * EPB + (tid >> 6);
    const int col  = hor ? be : (be + L2C);

    for (int j = tid; j < FOUTC * FINC * KC; j += BLOCK) Wsh[j] = W[j];

    const unsigned char probe = mh[(size_t)(lane * 4 + 1)];
    const bool words = (__ballot(probe != 0) == 0ull);

    __syncthreads();

    unsigned long long myb = 0;
    if (words) {
        const unsigned int* mw = reinterpret_cast<const unsigned int*>(mask)
                                 + (size_t)be * 832 + lane;
#pragma unroll
        for (int t = 0; t < KC; ++t) {
            unsigned long long bal = __ballot(mw[t * 64] != 0u);
            if (lane == t) myb = bal;
        }
    } else {
        const unsigned char* mb = mask + (size_t)be * 832 + lane;
#pragma unroll
        for (int t = 0; t < KC; ++t) {
            unsigned long long bal = __ballot(mb[t * 64] != 0);
            if (lane == t) myb = bal;
        }
    }

    int cols[KC];
#pragma unroll
    for (int k = 0; k < KC; ++k) cols[k] = ker[(size_t)be * KC + k];

    const int s     = lane * KC;
    const int u0    = s >> 6;
    const int shift = s & 63;
    unsigned long long lo = __shfl(myb, u0);
    unsigned long long hi = __shfl(myb, u0 + 1);
    unsigned int mbits = (unsigned int)(lo >> shift);
    if (shift) mbits |= (unsigned int)(hi << (64 - shift));
    mbits &= 0x1FFFu;

    float acc = 0.0f;
#pragma unroll
    for (int k = 0; k < KC; ++k) {
        const float xv = xt[((size_t)cols[k] << 3) + i];
        const float wk = Wsh[lane * KC + k];
        const float wm = ((mbits >> k) & 1u) ? wk : 0.0f;
        acc = fmaf(wm, xv, acc);
    }

    acc += __shfl_xor(acc, 1);
    acc += __shfl_xor(acc, 2);
    acc += __shfl_xor(acc, 4);

    if (i == 0) {
        const float z   = acc + bias[o];
        const float sig = 1.0f / (1.0f + __expf(-z));
        out[(size_t)o * NC + col] = (sig - 0.5f) * SCALE_F;
    }
}

extern "C" void kernel_launch(void* const* d_in, const int* in_sizes, int n_in,
                              void* d_out, int out_size, void* d_ws, size_t ws_size,
                              hipStream_t stream) {
    const float*         x   = (const float*)d_in[0];
    const float*         Wh  = (const float*)d_in[1];
    const float*         Wv  = (const float*)d_in[2];
    const float*         bh  = (const float*)d_in[3];
    const float*         bv  = (const float*)d_in[4];
    const unsigned char* mh  = (const unsigned char*)d_in[5];
    const unsigned char* mv  = (const unsigned char*)d_in[6];
    const int*           kh  = (const int*)d_in[7];
    const int*           kv  = (const int*)d_in[8];
    float* out = (float*)d_out;
    float* xt  = (float*)d_ws;

    transpose_x_kernel<<<NC / 256, 256, 0, stream>>>(x, xt);

    const size_t needed = XT_BYTES + 2 * BITMAP_BYTES_PER_BRANCH + 64;
    if (ws_size >= needed) {
        unsigned char* bm = (unsigned char*)d_ws + XT_BYTES;
        pack_mask_kernel<<<(unsigned)((2 * PACK_THREADS_PER_BRANCH) / 256), 256, 0, stream>>>(
            mh, mv, bm);
        edge_conv_bitmap_kernel<<<NC / EPB, BLOCK, 0, stream>>>(
            xt, Wh, Wv, bh, bv, bm, kh, kv, out);
    } else {
        edge_conv_kernel<<<NC / EPB, BLOCK, 0, stream>>>(
            xt, Wh, Wv, bh, bv, mh, mv, kh, kv, out);
    }
}

// Round 3
// 458.732 us; speedup vs baseline: 1.0893x; 1.0893x over previous
//
#include <hip/hip_runtime.h>
#include <math.h>

#define L2C   65536
#define NC    (2 * L2C)
#define FINC  8
#define FOUTC 8
#define KC    13
#define BLOCK 256         // 4 waves = 4 edges per block (1 edge per wave)
#define EPB   4
#define EWORDS (FOUTC * FINC * KC)   // 832 mask elements per edge

constexpr double E_D = 2.71828182845904523536;
constexpr float SCALE_F = (float)((2.0 + 2.0 * E_D) / (E_D - 1.0));

// d_ws: xt = x transposed to (N, FIN), 4 MiB at offset 0.

// x (FIN, N) -> xt (N, FIN): a gathered column becomes one 32 B segment.
__global__ __launch_bounds__(256)
void transpose_x_kernel(const float* __restrict__ x, float* __restrict__ xt) {
    int n = blockIdx.x * 256 + threadIdx.x;
    float v[FINC];
#pragma unroll
    for (int i = 0; i < FINC; ++i) v[i] = x[(size_t)i * NC + n];
    float4* dst = reinterpret_cast<float4*>(xt + ((size_t)n << 3));
    dst[0] = make_float4(v[0], v[1], v[2], v[3]);
    dst[1] = make_float4(v[4], v[5], v[6], v[7]);
}

// R10: key realization — mask layout [e][o][i][k] means lane (o*8+i)'s 13
// words are CONTIGUOUS at e*832 + lane*13. The R3/R8 ballot chain (R1: the
// latency bottleneck) and the R9 pack pass (R2: 131 us, itself latency-bound
// at 1 load/thread) were both servicing a coalescing problem that LDS
// staging solves for free:
//   - stage the block's 4 contiguous edges (13312 B) via dwordx4 loads
//     (16 B/lane, fully coalesced, 13 loads in flight per lane -> ILP),
//   - each lane reads its 13 words from LDS at lane*13+k: for fixed k,
//     13*lane mod 32 is a bijection (gcd(13,32)=1) -> 2 lanes/bank -> free.
//   - mask word feeds the FMA as a direct select; no bit-packing at all.
// ker loads hoisted to the top (head of the ker -> xt-gather -> FMA chain).
__global__ __launch_bounds__(BLOCK)
void edge_conv_kernel(const float* __restrict__ xt,
                      const float* __restrict__ Wh, const float* __restrict__ Wv,
                      const float* __restrict__ bh, const float* __restrict__ bv,
                      const unsigned char* __restrict__ mh,
                      const unsigned char* __restrict__ mv,
                      const int* __restrict__ kh, const int* __restrict__ kv,
                      float* __restrict__ out)
{
    __shared__ float        Wsh[EWORDS];          // 3328 B, flat [o][i][k]
    __shared__ unsigned int msh[EPB * EWORDS];    // 13312 B (words) / 3328 B (bool bytes)

    const int tid  = threadIdx.x;
    const int lane = tid & 63;
    const int wave = tid >> 6;
    const int o    = lane >> 3;
    const int i    = lane & 7;

    const int blk = blockIdx.x;
    const int blocks_per_branch = L2C / EPB;   // 16384
    const bool hor = (blk < blocks_per_branch);

    const float*         W    = hor ? Wh  : Wv;
    const float*         bias = hor ? bh  : bv;
    const unsigned char* mask = hor ? mh  : mv;
    const int*           ker  = hor ? kh  : kv;
    const int bblk = hor ? blk : blk - blocks_per_branch;
    const int be   = bblk * EPB + wave;        // edge index within branch
    const int col  = hor ? be : (be + L2C);    // edge lists are arange / arange+L2

    // 1) kernel column indices first — longest dependency chain in the kernel
    //    (ker load -> xt gather -> FMA). Wave-uniform address, broadcast.
    int cols[KC];
#pragma unroll
    for (int k = 0; k < KC; ++k) cols[k] = ker[(size_t)be * KC + k];

    // Mask-encoding probe (proven R3/R8 logic): for int32/float32 0/1 masks
    // every byte at offset%4==1 is zero; for 1-byte bools they're random 0/1.
    // Grid-uniform (every wave reads the same 256 B window of mh).
    const unsigned char probe = mh[(size_t)(lane * 4 + 1)];
    const bool words = (__ballot(probe != 0) == 0ull);

    // 2) stage this block's 4 contiguous edges of mask into LDS, dwordx4.
    if (words) {
        const uint4* g4 = reinterpret_cast<const uint4*>(
            mask + (size_t)bblk * (EPB * EWORDS * 4));   // 13312 B, 16B-aligned
        uint4* m4 = reinterpret_cast<uint4*>(msh);
#pragma unroll
        for (int idx = tid; idx < EPB * EWORDS / 4; idx += BLOCK)  // 832 uint4
            m4[idx] = g4[idx];
    } else {
        const uint4* g4 = reinterpret_cast<const uint4*>(
            mask + (size_t)bblk * (EPB * EWORDS));       // 3328 B of bool bytes
        uint4* m4 = reinterpret_cast<uint4*>(msh);
        if (tid < EPB * EWORDS / 16)                     // 208 uint4
            m4[tid] = g4[tid];
    }

    // 3) weights: 832 floats = 208 float4.
    if (tid < EWORDS / 4)
        reinterpret_cast<float4*>(Wsh)[tid] = reinterpret_cast<const float4*>(W)[tid];

    __syncthreads();

    // 4) compute. Lane's mask words are lane-local in LDS; 2-acc for ILP.
    float acc0 = 0.0f, acc1 = 0.0f;
    if (words) {
        const unsigned int* mrow = msh + wave * EWORDS + lane * KC;
#pragma unroll
        for (int k = 0; k < KC; ++k) {
            const float xv = xt[((size_t)cols[k] << 3) + i];   // one 32 B seg / wave / k
            const float wk = Wsh[lane * KC + k];               // 2-way LDS alias: free
            const float wm = mrow[k] ? wk : 0.0f;
            if (k & 1) acc1 = fmaf(wm, xv, acc1);
            else       acc0 = fmaf(wm, xv, acc0);
        }
    } else {
        const unsigned char* mrow = reinterpret_cast<const unsigned char*>(msh)
                                    + wave * EWORDS + lane * KC;
#pragma unroll
        for (int k = 0; k < KC; ++k) {
            const float xv = xt[((size_t)cols[k] << 3) + i];
            const float wk = Wsh[lane * KC + k];
            const float wm = mrow[k] ? wk : 0.0f;
            if (k & 1) acc1 = fmaf(wm, xv, acc1);
            else       acc0 = fmaf(wm, xv, acc0);
        }
    }
    float acc = acc0 + acc1;

    // Reduce over i (lanes o*8 .. o*8+7).
    acc += __shfl_xor(acc, 1);
    acc += __shfl_xor(acc, 2);
    acc += __shfl_xor(acc, 4);

    if (i == 0) {
        const float z   = acc + bias[o];
        const float sig = 1.0f / (1.0f + __expf(-z));
        out[(size_t)o * NC + col] = (sig - 0.5f) * SCALE_F;
    }
}

extern "C" void kernel_launch(void* const* d_in, const int* in_sizes, int n_in,
                              void* d_out, int out_size, void* d_ws, size_t ws_size,
                              hipStream_t stream) {
    const float*         x   = (const float*)d_in[0];
    const float*         Wh  = (const float*)d_in[1];
    const float*         Wv  = (const float*)d_in[2];
    const float*         bh  = (const float*)d_in[3];
    const float*         bv  = (const float*)d_in[4];
    const unsigned char* mh  = (const unsigned char*)d_in[5];
    const unsigned char* mv  = (const unsigned char*)d_in[6];
    const int*           kh  = (const int*)d_in[7];
    const int*           kv  = (const int*)d_in[8];
    float* out = (float*)d_out;
    float* xt  = (float*)d_ws;

    transpose_x_kernel<<<NC / 256, 256, 0, stream>>>(x, xt);
    edge_conv_kernel<<<NC / EPB, BLOCK, 0, stream>>>(
        xt, Wh, Wv, bh, bv, mh, mv, kh, kv, out);
}